// Round 13
// baseline (94.093 us; speedup 1.0000x reference)
//
#include <hip/hip_runtime.h>

#define NN 8192
#define DD 128
#define BI 128            // i-rows per block panel
#define BJ 64             // j-cols per inner tile
#define NT 16             // j-tiles per block
#define GXX 8             // j-strips
#define GYY 64            // i-panels
#define NBLK (GXX * GYY)  // 512 blocks = exactly 2/CU, ONE generation

typedef __attribute__((ext_vector_type(8))) short bf16x8;
typedef __attribute__((ext_vector_type(4))) float f32x4;

__device__ __forceinline__ ushort f2bf(float x) {
    unsigned u = __float_as_uint(x);
    unsigned r = u + 0x7FFFu + ((u >> 16) & 1u);
    return (ushort)(r >> 16);
}

__device__ __forceinline__ void async16(void* lds, const void* g) {
    __builtin_amdgcn_global_load_lds(
        (const __attribute__((address_space(1))) unsigned*)g,
        (__attribute__((address_space(3))) unsigned*)lds, 16, 0, 0);
}
__device__ __forceinline__ void async4(void* lds, const void* g) {
    __builtin_amdgcn_global_load_lds(
        (const __attribute__((address_space(1))) unsigned*)g,
        (__attribute__((address_space(3))) unsigned*)lds, 4, 0, 0);
}

// Kernel 0: sq[i] = ||f_i||^2 (always); Fbf = bf16(F) (if doFbf).
__global__ void prep_kernel(const float* __restrict__ F, ushort* __restrict__ Fbf,
                            float* __restrict__ sq, int doFbf) {
    int gtid = blockIdx.x * blockDim.x + threadIdx.x;
    int row  = gtid >> 6;
    int lane = threadIdx.x & 63;
    const float2 v = *(const float2*)(F + (size_t)row * DD + lane * 2);
    if (doFbf)
        ((ushort2*)(Fbf + (size_t)row * DD))[lane] = make_ushort2(f2bf(v.x), f2bf(v.y));
    float s = v.x * v.x + v.y * v.y;
    #pragma unroll
    for (int off = 32; off > 0; off >>= 1) s += __shfl_down(s, off);
    if (lane == 0) sq[row] = s;
}

// One loop iteration. SVC/SJC: S+sqj regs being consumed (tile T, prefetched
// in iter T-1). SVN/SJN: regs to prefetch tile T+1 into. RB: lJ buffer holding
// tile T; WB: buffer to stage tile T+1 into. vmcnt(5) at the end retires the
// 2 staging loads but keeps the 5 prefetch loads in flight across s_barrier.
#define BODY(T, SVC, SJC, SVN, SJN, RB, WB)                                   \
  {                                                                           \
    const int t_ = (T);                                                       \
    if (t_ < NT - 1) {                                                        \
      const int gjn = jbase + (t_ + 1) * BJ;                                  \
      _Pragma("unroll")                                                       \
      for (int it = 0; it < 2; ++it) {                                        \
        const int c_ = it * 8 + w;                                            \
        const int row_ = c_ * 4 + (l >> 4);                                   \
        const int src_ = ((l & 15) * 16) ^ ((row_ & 7) << 4);                 \
        async16((char*)(WB) + c_ * 1024,                                      \
                (const char*)(Fbf + (size_t)(gjn + row_) * DD) + src_);       \
      }                                                                       \
      __builtin_amdgcn_sched_barrier(0);                                      \
      const float* sbn_ = S + (size_t)(gi + ih + fr) * NN + gjn + jw + g * 4; \
      _Pragma("unroll")                                                       \
      for (int c = 0; c < 4; ++c)                                             \
        SVN[c] = *(const f32x4*)(sbn_ + (size_t)c * 16 * NN);                 \
      SJN = *(const float4*)(sq + gjn + jw + g * 4);                          \
      __builtin_amdgcn_sched_barrier(0);                                      \
    }                                                                         \
    bf16x8 af_[4];                                                            \
    {                                                                         \
      const int row_ = jw + fr;                                               \
      const int sw_ = (row_ & 7) << 4;                                        \
      _Pragma("unroll")                                                       \
      for (int kk = 0; kk < 4; ++kk)                                          \
        af_[kk] = *(const bf16x8*)((const char*)(RB) + row_ * 256 +           \
                                   ((kk * 64 + g * 16) ^ sw_));               \
    }                                                                         \
    f32x4 acc_[4];                                                            \
    _Pragma("unroll")                                                         \
    for (int c = 0; c < 4; ++c) acc_[c] = (f32x4){0.f, 0.f, 0.f, 0.f};        \
    _Pragma("unroll")                                                         \
    for (int c = 0; c < 4; ++c) {                                             \
      const int row_ = ih + c * 16 + fr;                                      \
      const int sw_ = (row_ & 7) << 4;                                        \
      _Pragma("unroll")                                                       \
      for (int kk = 0; kk < 4; ++kk) {                                        \
        const bf16x8 bfr_ = *(const bf16x8*)((const char*)lI + row_ * 256 +   \
                                             ((kk * 64 + g * 16) ^ sw_));     \
        acc_[c] = __builtin_amdgcn_mfma_f32_16x16x32_bf16(af_[kk], bfr_,      \
                                                          acc_[c], 0, 0, 0);  \
      }                                                                       \
    }                                                                         \
    _Pragma("unroll")                                                         \
    for (int c = 0; c < 4; ++c) {                                             \
      const float sic_ = sqi[ih + c * 16 + fr];                               \
      const f32x4 s4_ = SVC[c];                                               \
      part0 += s4_.x * ((sic_ + SJC.x) - 2.f * acc_[c][0]);                   \
      part1 += s4_.y * ((sic_ + SJC.y) - 2.f * acc_[c][1]);                   \
      part0 += s4_.z * ((sic_ + SJC.z) - 2.f * acc_[c][2]);                   \
      part1 += s4_.w * ((sic_ + SJC.w) - 2.f * acc_[c][3]);                   \
    }                                                                         \
    if (t_ < NT - 1) {                                                        \
      asm volatile("s_waitcnt vmcnt(5)" ::: "memory");                        \
      __builtin_amdgcn_sched_barrier(0);                                      \
      __builtin_amdgcn_s_barrier();                                           \
      __builtin_amdgcn_sched_barrier(0);                                      \
    }                                                                         \
  }

// Fast path: persistent block = fixed 128-row F_i panel x 1024 S-columns.
// 16 inner j-tiles (64 cols): lJ double-buffered, S prefetched into regs one
// full iteration ahead -> consume never waits on HBM; barrier never drains S.
__global__ __launch_bounds__(512, 4) void tile_kernel(
        const ushort* __restrict__ Fbf, const float* __restrict__ S,
        const float* __restrict__ sq, float* __restrict__ partials) {
    __shared__ ushort lI[BI * DD];    // 32 KB, staged once
    __shared__ ushort lJ0[BJ * DD];   // 16 KB dbuf
    __shared__ ushort lJ1[BJ * DD];   // 16 KB dbuf
    __shared__ float  sqi[BI];
    __shared__ float  red[8];

    const int gi    = blockIdx.y * BI;
    const int jbase = blockIdx.x * (NT * BJ);
    const int tid = threadIdx.x;
    const int w = tid >> 6, l = tid & 63;
    const int fr = l & 15, g = l >> 4;
    const int jw = (w & 3) * 16;      // wave's 16-col j window within 64-col tile
    const int ih = (w >> 2) * 64;     // wave's i-half (0 or 64)

    // ---- prologue: stage lI (4/thread) + lJ0 (2/thread) + sqi ----
    #pragma unroll
    for (int it = 0; it < 4; ++it) {
        const int c = it * 8 + w;
        const int row = c * 4 + (l >> 4);
        const int src = ((l & 15) * 16) ^ ((row & 7) << 4);
        async16((char*)lI + c * 1024, (const char*)(Fbf + (size_t)(gi + row) * DD) + src);
    }
    #pragma unroll
    for (int it = 0; it < 2; ++it) {
        const int c = it * 8 + w;
        const int row = c * 4 + (l >> 4);
        const int src = ((l & 15) * 16) ^ ((row & 7) << 4);
        async16((char*)lJ0 + c * 1024, (const char*)(Fbf + (size_t)(jbase + row) * DD) + src);
    }
    if (w < 2) {
        float* dstb = sqi + w * 64;
        async4(dstb, sq + gi + w * 64 + l);
    }
    __builtin_amdgcn_sched_barrier(0);

    // ---- prefetch S/sqj for tile 0 ----
    f32x4 svA[4], svB[4];
    float4 sjA, sjB;
    {
        const float* sb0 = S + (size_t)(gi + ih + fr) * NN + jbase + jw + g * 4;
        #pragma unroll
        for (int c = 0; c < 4; ++c)
            svA[c] = *(const f32x4*)(sb0 + (size_t)c * 16 * NN);
        sjA = *(const float4*)(sq + jbase + jw + g * 4);
    }
    __builtin_amdgcn_sched_barrier(0);
    asm volatile("s_waitcnt vmcnt(5)" ::: "memory");   // staging retired; S[0] in flight
    __builtin_amdgcn_sched_barrier(0);
    __builtin_amdgcn_s_barrier();
    __builtin_amdgcn_sched_barrier(0);

    float part0 = 0.f, part1 = 0.f;
    for (int t = 0; t < NT; t += 2) {
        BODY(t,     svA, sjA, svB, sjB, lJ0, lJ1);
        BODY(t + 1, svB, sjB, svA, sjA, lJ1, lJ0);
    }

    // ---- deterministic block reduction ----
    float part = part0 + part1;
    #pragma unroll
    for (int off = 32; off > 0; off >>= 1) part += __shfl_down(part, off);
    if (l == 0) red[w] = part;
    __syncthreads();
    if (tid == 0)
        partials[blockIdx.y * gridDim.x + blockIdx.x] =
            ((red[0] + red[1]) + (red[2] + red[3])) +
            ((red[4] + red[5]) + (red[6] + red[7]));
}

// ---------------- fallback path (tiny workspace): R2-style ----------------
__global__ __launch_bounds__(256, 2) void tile_fb_kernel(
        const float* __restrict__ F, const float* __restrict__ S,
        const float* __restrict__ sq, float* __restrict__ partials) {
    __shared__ ushort lI[BI * DD];
    __shared__ ushort lJ[BI * DD];
    __shared__ float  sqi[BI];
    __shared__ float  sqj[BI];
    __shared__ float  red[4];

    const int gi = blockIdx.y * BI, gj = blockIdx.x * BI;
    const int tid = threadIdx.x;
    const int w = tid >> 6, l = tid & 63;

    const int r0 = tid >> 5;
    const int c4 = (tid & 31) * 4;
    #pragma unroll
    for (int it = 0; it < 16; ++it) {
        const int row = it * 8 + r0;
        const float4 va = *(const float4*)(F + (size_t)(gi + row) * DD + c4);
        const float4 vb = *(const float4*)(F + (size_t)(gj + row) * DD + c4);
        int byte = row * 256 + c4 * 2;
        byte ^= (row & 7) << 4;
        *(ushort4*)((char*)lI + byte) =
            make_ushort4(f2bf(va.x), f2bf(va.y), f2bf(va.z), f2bf(va.w));
        *(ushort4*)((char*)lJ + byte) =
            make_ushort4(f2bf(vb.x), f2bf(vb.y), f2bf(vb.z), f2bf(vb.w));
    }
    if (tid < 128) sqi[tid] = sq[gi + tid];
    else           sqj[tid - 128] = sq[gj + tid - 128];
    __syncthreads();

    const int fr = l & 15;
    const int g  = l >> 4;
    const int jw = w * 32;

    float4 sv0[8], sv1[8];
    #pragma unroll
    for (int ct = 0; ct < 8; ++ct) {
        const float* srow = S + (size_t)(gi + ct * 16 + fr) * NN + gj + jw + g * 4;
        sv0[ct] = *(const float4*)(srow);
        sv1[ct] = *(const float4*)(srow + 16);
    }

    bf16x8 afrag[2][4];
    #pragma unroll
    for (int kk = 0; kk < 4; ++kk) {
        int row = jw + fr;
        int byte = row * 256 + kk * 64 + g * 16; byte ^= (row & 7) << 4;
        afrag[0][kk] = *(const bf16x8*)((const char*)lJ + byte);
        row = jw + 16 + fr;
        byte = row * 256 + kk * 64 + g * 16; byte ^= (row & 7) << 4;
        afrag[1][kk] = *(const bf16x8*)((const char*)lJ + byte);
    }

    f32x4 acc[2][8];
    #pragma unroll
    for (int ct = 0; ct < 8; ++ct) {
        acc[0][ct] = (f32x4){0.f, 0.f, 0.f, 0.f};
        acc[1][ct] = (f32x4){0.f, 0.f, 0.f, 0.f};
    }
    #pragma unroll
    for (int ct = 0; ct < 8; ++ct) {
        #pragma unroll
        for (int kk = 0; kk < 4; ++kk) {
            const int row = ct * 16 + fr;
            int byte = row * 256 + kk * 64 + g * 16; byte ^= (row & 7) << 4;
            const bf16x8 bfrag = *(const bf16x8*)((const char*)lI + byte);
            acc[0][ct] = __builtin_amdgcn_mfma_f32_16x16x32_bf16(afrag[0][kk], bfrag, acc[0][ct], 0, 0, 0);
            acc[1][ct] = __builtin_amdgcn_mfma_f32_16x16x32_bf16(afrag[1][kk], bfrag, acc[1][ct], 0, 0, 0);
        }
    }

    const float4 sj0 = *(const float4*)(sqj + jw + g * 4);
    const float4 sj1 = *(const float4*)(sqj + jw + 16 + g * 4);
    float part = 0.f;
    #pragma unroll
    for (int ct = 0; ct < 8; ++ct) {
        const float sic = sqi[ct * 16 + fr];
        const float4 s0 = sv0[ct], s1 = sv1[ct];
        part += s0.x * (sic + sj0.x - 2.f * acc[0][ct][0]);
        part += s0.y * (sic + sj0.y - 2.f * acc[0][ct][1]);
        part += s0.z * (sic + sj0.z - 2.f * acc[0][ct][2]);
        part += s0.w * (sic + sj0.w - 2.f * acc[0][ct][3]);
        part += s1.x * (sic + sj1.x - 2.f * acc[1][ct][0]);
        part += s1.y * (sic + sj1.y - 2.f * acc[1][ct][1]);
        part += s1.z * (sic + sj1.z - 2.f * acc[1][ct][2]);
        part += s1.w * (sic + sj1.w - 2.f * acc[1][ct][3]);
    }

    #pragma unroll
    for (int off = 32; off > 0; off >>= 1) part += __shfl_down(part, off);
    if (l == 0) red[w] = part;
    __syncthreads();
    if (tid == 0)
        partials[blockIdx.y * gridDim.x + blockIdx.x] = (red[0] + red[1]) + (red[2] + red[3]);
}

__global__ void reduce_kernel(const float* __restrict__ partials, float* __restrict__ out, int n) {
    __shared__ float sm[256];
    const int t = threadIdx.x;
    float s = 0.f;
    for (int i = t; i < n; i += 256) s += partials[i];
    sm[t] = s;
    __syncthreads();
    for (int off = 128; off > 0; off >>= 1) {
        if (t < off) sm[t] += sm[t + off];
        __syncthreads();
    }
    if (t == 0) out[0] = sm[0];
}

extern "C" void kernel_launch(void* const* d_in, const int* in_sizes, int n_in,
                              void* d_out, int out_size, void* d_ws, size_t ws_size,
                              hipStream_t stream) {
    const float* F = (const float*)d_in[0];
    const float* S = (const float*)d_in[1];
    float* sq       = (float*)d_ws;                       // 32 KB
    float* partials = sq + NN;                            // 16 KB
    ushort* Fbf     = (ushort*)((char*)d_ws + 48 * 1024); // 2 MB
    float* out      = (float*)d_out;

    const size_t need = 48 * 1024 + (size_t)NN * DD * 2 + 256;
    const int fast = (ws_size >= need) ? 1 : 0;

    prep_kernel<<<NN / 4, 256, 0, stream>>>(F, Fbf, sq, fast);
    if (fast) {
        tile_kernel<<<dim3(GXX, GYY), 512, 0, stream>>>(Fbf, S, sq, partials);
        reduce_kernel<<<1, 256, 0, stream>>>(partials, out, NBLK);
    } else {
        tile_fb_kernel<<<dim3(GYY, GYY), 256, 0, stream>>>(F, S, sq, partials);
        reduce_kernel<<<1, 256, 0, stream>>>(partials, out, GYY * GYY);
    }
}

// Round 14
// 72.531 us; speedup vs baseline: 1.2973x; 1.2973x over previous
//
#include <hip/hip_runtime.h>

#define NN 8192
#define DD 128
#define BM 128
#define NTILE (NN / BM)   // 64
#define NWG (NTILE * NTILE)  // 4096 blocks
#define NXCD 8

typedef __attribute__((ext_vector_type(8))) short bf16x8;
typedef __attribute__((ext_vector_type(4))) float f32x4;

__device__ __forceinline__ ushort f2bf(float x) {
    unsigned u = __float_as_uint(x);
    unsigned r = u + 0x7FFFu + ((u >> 16) & 1u);
    return (ushort)(r >> 16);
}

__device__ __forceinline__ void async16(void* lds, const void* g) {
    __builtin_amdgcn_global_load_lds(
        (const __attribute__((address_space(1))) unsigned*)g,
        (__attribute__((address_space(3))) unsigned*)lds, 16, 0, 0);
}
__device__ __forceinline__ void async4(void* lds, const void* g) {
    __builtin_amdgcn_global_load_lds(
        (const __attribute__((address_space(1))) unsigned*)g,
        (__attribute__((address_space(3))) unsigned*)lds, 4, 0, 0);
}

// Kernel 0: sq[i] = ||f_i||^2 (always); Fbf = bf16(F) (if doFbf).
__global__ void prep_kernel(const float* __restrict__ F, ushort* __restrict__ Fbf,
                            float* __restrict__ sq, int doFbf) {
    int gtid = blockIdx.x * blockDim.x + threadIdx.x;
    int row  = gtid >> 6;
    int lane = threadIdx.x & 63;
    const float2 v = *(const float2*)(F + (size_t)row * DD + lane * 2);
    if (doFbf)
        ((ushort2*)(Fbf + (size_t)row * DD))[lane] = make_ushort2(f2bf(v.x), f2bf(v.y));
    float s = v.x * v.x + v.y * v.y;
    #pragma unroll
    for (int off = 32; off > 0; off >>= 1) s += __shfl_down(s, off);
    if (lane == 0) sq[row] = s;
}

// Kernel 1 (fast): R10 winner (measured 64.1us) + bijective XCD swizzle.
// 1-D grid of 4096; orig%8 = XCD (round-robin dispatch), so wgid =
// (orig%8)*512 + orig/8 gives each XCD a contiguous range of 512 tiles =
// 8 full i-stripes processed bx-sequentially: the XCD sweeps one 4MB
// S-stripe linearly (DRAM page locality) and its ~64 co-resident blocks
// share the same lI panel (L2 reuse).
__global__ __launch_bounds__(512, 4) void tile_kernel(
        const ushort* __restrict__ Fbf, const float* __restrict__ S,
        const float* __restrict__ sq, float* __restrict__ partials) {
    __shared__ ushort lI[BM * DD];   // F_i panel (B-operand), swizzled (32 KB)
    __shared__ ushort lJ[BM * DD];   // F_j panel (A-operand), swizzled (32 KB)
    __shared__ float  sqi[BM];
    __shared__ float  sqj[BM];
    __shared__ float  red[8];

    const int orig = blockIdx.x;
    const int wgid = (orig & (NXCD - 1)) * (NWG / NXCD) + (orig >> 3);
    const int by = wgid >> 6;          // i-stripe
    const int bx = wgid & 63;          // j-tile
    const int gi = by * BM, gj = bx * BM;
    const int tid = threadIdx.x;
    const int w = tid >> 6, l = tid & 63;

    // ---- stage panels: linear LDS dest, pre-swizzled global src ----
    #pragma unroll
    for (int it = 0; it < 4; ++it) {
        const int chunk = it * 8 + w;            // 1 KB chunks, 32 per panel
        const int row = chunk * 4 + (l >> 4);    // LDS row this lane lands in
        const int src = ((l & 15) * 16) ^ ((row & 7) << 4);
        async16((char*)lI + chunk * 1024, (const char*)(Fbf + (size_t)(gi + row) * DD) + src);
        async16((char*)lJ + chunk * 1024, (const char*)(Fbf + (size_t)(gj + row) * DD) + src);
    }
    if (w < 4) {
        float* dstb = (w < 2 ? sqi : sqj) + (w & 1) * 64;
        const float* srcb = sq + (w < 2 ? gi : gj) + (w & 1) * 64 + l;
        async4(dstb, srcb);
    }
    __syncthreads();

    const int fr = l & 15;
    const int g  = l >> 4;
    const int jw = w * 16;            // wave's 16-col j window in tile

    // ---- S loads after barrier: fly under ds_reads + MFMAs ----
    f32x4 sv[8];
    const float* sb = S + (size_t)(gi + fr) * NN + gj + jw + g * 4;
    #pragma unroll
    for (int ct = 0; ct < 8; ++ct)
        sv[ct] = *(const f32x4*)(sb + (size_t)ct * 16 * NN);
    __builtin_amdgcn_sched_barrier(0);   // pin: S issued before MFMA/ds_read

    // ---- A fragments from F_j panel ----
    bf16x8 afrag[4];
    #pragma unroll
    for (int kk = 0; kk < 4; ++kk) {
        const int row = jw + fr;
        int byte = row * 256 + kk * 64 + g * 16;
        byte ^= (row & 7) << 4;
        afrag[kk] = *(const bf16x8*)((const char*)lJ + byte);
    }

    f32x4 acc[8];
    #pragma unroll
    for (int ct = 0; ct < 8; ++ct) acc[ct] = (f32x4){0.f, 0.f, 0.f, 0.f};

    // ---- MFMA: D = F_j . F_i^T (S loads in flight underneath) ----
    #pragma unroll
    for (int ct = 0; ct < 8; ++ct) {
        const int row = ct * 16 + fr;
        const int sw  = (row & 7) << 4;
        #pragma unroll
        for (int kk = 0; kk < 4; ++kk) {
            const bf16x8 bfrag = *(const bf16x8*)((const char*)lI + row * 256 +
                                                  ((kk * 64 + g * 16) ^ sw));
            acc[ct] = __builtin_amdgcn_mfma_f32_16x16x32_bf16(afrag[kk], bfrag, acc[ct], 0, 0, 0);
        }
    }

    // ---- consume: part += S * (sq_i + sq_j - 2*P) ----
    const float4 sjv = *(const float4*)(sqj + jw + g * 4);
    float part0 = 0.f, part1 = 0.f;
    #pragma unroll
    for (int ct = 0; ct < 8; ++ct) {
        const float sic = sqi[ct * 16 + fr];
        const f32x4 s4 = sv[ct];
        part0 += s4.x * ((sic + sjv.x) - 2.f * acc[ct][0]);
        part1 += s4.y * ((sic + sjv.y) - 2.f * acc[ct][1]);
        part0 += s4.z * ((sic + sjv.z) - 2.f * acc[ct][2]);
        part1 += s4.w * ((sic + sjv.w) - 2.f * acc[ct][3]);
    }
    float part = part0 + part1;

    // ---- deterministic block reduction ----
    #pragma unroll
    for (int off = 32; off > 0; off >>= 1) part += __shfl_down(part, off);
    if (l == 0) red[w] = part;
    __syncthreads();
    if (tid == 0)
        partials[wgid] =
            ((red[0] + red[1]) + (red[2] + red[3])) +
            ((red[4] + red[5]) + (red[6] + red[7]));
}

// ---------------- fallback path (tiny workspace): R2-style ----------------
__global__ __launch_bounds__(256, 2) void tile_fb_kernel(
        const float* __restrict__ F, const float* __restrict__ S,
        const float* __restrict__ sq, float* __restrict__ partials) {
    __shared__ ushort lI[BM * DD];
    __shared__ ushort lJ[BM * DD];
    __shared__ float  sqi[BM];
    __shared__ float  sqj[BM];
    __shared__ float  red[4];

    const int gi = blockIdx.y * BM, gj = blockIdx.x * BM;
    const int tid = threadIdx.x;
    const int w = tid >> 6, l = tid & 63;

    const int r0 = tid >> 5;
    const int c4 = (tid & 31) * 4;
    #pragma unroll
    for (int it = 0; it < 16; ++it) {
        const int row = it * 8 + r0;
        const float4 va = *(const float4*)(F + (size_t)(gi + row) * DD + c4);
        const float4 vb = *(const float4*)(F + (size_t)(gj + row) * DD + c4);
        int byte = row * 256 + c4 * 2;
        byte ^= (row & 7) << 4;
        *(ushort4*)((char*)lI + byte) =
            make_ushort4(f2bf(va.x), f2bf(va.y), f2bf(va.z), f2bf(va.w));
        *(ushort4*)((char*)lJ + byte) =
            make_ushort4(f2bf(vb.x), f2bf(vb.y), f2bf(vb.z), f2bf(vb.w));
    }
    if (tid < 128) sqi[tid] = sq[gi + tid];
    else           sqj[tid - 128] = sq[gj + tid - 128];
    __syncthreads();

    const int fr = l & 15;
    const int g  = l >> 4;
    const int jw = w * 32;

    float4 sv0[8], sv1[8];
    #pragma unroll
    for (int ct = 0; ct < 8; ++ct) {
        const float* srow = S + (size_t)(gi + ct * 16 + fr) * NN + gj + jw + g * 4;
        sv0[ct] = *(const float4*)(srow);
        sv1[ct] = *(const float4*)(srow + 16);
    }

    bf16x8 afrag[2][4];
    #pragma unroll
    for (int kk = 0; kk < 4; ++kk) {
        int row = jw + fr;
        int byte = row * 256 + kk * 64 + g * 16; byte ^= (row & 7) << 4;
        afrag[0][kk] = *(const bf16x8*)((const char*)lJ + byte);
        row = jw + 16 + fr;
        byte = row * 256 + kk * 64 + g * 16; byte ^= (row & 7) << 4;
        afrag[1][kk] = *(const bf16x8*)((const char*)lJ + byte);
    }

    f32x4 acc[2][8];
    #pragma unroll
    for (int ct = 0; ct < 8; ++ct) {
        acc[0][ct] = (f32x4){0.f, 0.f, 0.f, 0.f};
        acc[1][ct] = (f32x4){0.f, 0.f, 0.f, 0.f};
    }
    #pragma unroll
    for (int ct = 0; ct < 8; ++ct) {
        #pragma unroll
        for (int kk = 0; kk < 4; ++kk) {
            const int row = ct * 16 + fr;
            int byte = row * 256 + kk * 64 + g * 16; byte ^= (row & 7) << 4;
            const bf16x8 bfrag = *(const bf16x8*)((const char*)lI + byte);
            acc[0][ct] = __builtin_amdgcn_mfma_f32_16x16x32_bf16(afrag[0][kk], bfrag, acc[0][ct], 0, 0, 0);
            acc[1][ct] = __builtin_amdgcn_mfma_f32_16x16x32_bf16(afrag[1][kk], bfrag, acc[1][ct], 0, 0, 0);
        }
    }

    const float4 sj0 = *(const float4*)(sqj + jw + g * 4);
    const float4 sj1 = *(const float4*)(sqj + jw + 16 + g * 4);
    float part = 0.f;
    #pragma unroll
    for (int ct = 0; ct < 8; ++ct) {
        const float sic = sqi[ct * 16 + fr];
        const float4 s0 = sv0[ct], s1 = sv1[ct];
        part += s0.x * (sic + sj0.x - 2.f * acc[0][ct][0]);
        part += s0.y * (sic + sj0.y - 2.f * acc[0][ct][1]);
        part += s0.z * (sic + sj0.z - 2.f * acc[0][ct][2]);
        part += s0.w * (sic + sj0.w - 2.f * acc[0][ct][3]);
        part += s1.x * (sic + sj1.x - 2.f * acc[1][ct][0]);
        part += s1.y * (sic + sj1.y - 2.f * acc[1][ct][1]);
        part += s1.z * (sic + sj1.z - 2.f * acc[1][ct][2]);
        part += s1.w * (sic + sj1.w - 2.f * acc[1][ct][3]);
    }

    #pragma unroll
    for (int off = 32; off > 0; off >>= 1) part += __shfl_down(part, off);
    if (l == 0) red[w] = part;
    __syncthreads();
    if (tid == 0)
        partials[blockIdx.y * gridDim.x + blockIdx.x] = (red[0] + red[1]) + (red[2] + red[3]);
}

__global__ void reduce_kernel(const float* __restrict__ partials, float* __restrict__ out) {
    __shared__ float sm[256];
    const int t = threadIdx.x;
    float s = 0.f;
    for (int i = t; i < NTILE * NTILE; i += 256) s += partials[i];
    sm[t] = s;
    __syncthreads();
    for (int off = 128; off > 0; off >>= 1) {
        if (t < off) sm[t] += sm[t + off];
        __syncthreads();
    }
    if (t == 0) out[0] = sm[0];
}

extern "C" void kernel_launch(void* const* d_in, const int* in_sizes, int n_in,
                              void* d_out, int out_size, void* d_ws, size_t ws_size,
                              hipStream_t stream) {
    const float* F = (const float*)d_in[0];
    const float* S = (const float*)d_in[1];
    float* sq       = (float*)d_ws;                       // 32 KB
    float* partials = sq + NN;                            // 16 KB
    ushort* Fbf     = (ushort*)((char*)d_ws + 48 * 1024); // 2 MB
    float* out      = (float*)d_out;

    const size_t need = 48 * 1024 + (size_t)NN * DD * 2 + 256;
    const int fast = (ws_size >= need) ? 1 : 0;

    prep_kernel<<<NN / 4, 256, 0, stream>>>(F, Fbf, sq, fast);
    if (fast)
        tile_kernel<<<NWG, 512, 0, stream>>>(Fbf, S, sq, partials);
    else
        tile_fb_kernel<<<dim3(NTILE, NTILE), 256, 0, stream>>>(F, S, sq, partials);
    reduce_kernel<<<1, 256, 0, stream>>>(partials, out);
}

// Round 15
// 71.724 us; speedup vs baseline: 1.3119x; 1.0112x over previous
//
#include <hip/hip_runtime.h>

#define NN 8192
#define DD 128
#define BM 128
#define NTILE (NN / BM)   // 64

typedef __attribute__((ext_vector_type(8))) short bf16x8;
typedef __attribute__((ext_vector_type(4))) float f32x4;

__device__ __forceinline__ ushort f2bf(float x) {
    unsigned u = __float_as_uint(x);
    unsigned r = u + 0x7FFFu + ((u >> 16) & 1u);
    return (ushort)(r >> 16);
}

__device__ __forceinline__ void async16(void* lds, const void* g) {
    __builtin_amdgcn_global_load_lds(
        (const __attribute__((address_space(1))) unsigned*)g,
        (__attribute__((address_space(3))) unsigned*)lds, 16, 0, 0);
}
__device__ __forceinline__ void async4(void* lds, const void* g) {
    __builtin_amdgcn_global_load_lds(
        (const __attribute__((address_space(1))) unsigned*)g,
        (__attribute__((address_space(3))) unsigned*)lds, 4, 0, 0);
}

// Kernel 0: sq[i] = ||f_i||^2 (always); Fbf = bf16(F) (if doFbf).
__global__ void prep_kernel(const float* __restrict__ F, ushort* __restrict__ Fbf,
                            float* __restrict__ sq, int doFbf) {
    int gtid = blockIdx.x * blockDim.x + threadIdx.x;
    int row  = gtid >> 6;
    int lane = threadIdx.x & 63;
    const float2 v = *(const float2*)(F + (size_t)row * DD + lane * 2);
    if (doFbf)
        ((ushort2*)(Fbf + (size_t)row * DD))[lane] = make_ushort2(f2bf(v.x), f2bf(v.y));
    float s = v.x * v.x + v.y * v.y;
    #pragma unroll
    for (int off = 32; off > 0; off >>= 1) s += __shfl_down(s, off);
    if (lane == 0) sq[row] = s;
}

// Kernel 1 (fast): R10 winner (64.1us) with lJ panel ELIMINATED: each wave
// loads its 4 A-fragments (64B/thread) directly from L2-resident Fbf in the
// prologue (drained by the same barrier as lI staging). Staging volume per
// block halves (64KB -> 32KB) -> shorter barrier drain -> smaller per-block
// S-less window. S loads stay post-barrier, flying under the MFMA phase.
__global__ __launch_bounds__(512, 4) void tile_kernel(
        const ushort* __restrict__ Fbf, const float* __restrict__ S,
        const float* __restrict__ sq, float* __restrict__ partials) {
    __shared__ ushort lI[BM * DD];   // F_i panel (B-operand), swizzled (32 KB)
    __shared__ float  sqi[BM];
    __shared__ float  red[8];

    const int gi = blockIdx.y * BM, gj = blockIdx.x * BM;
    const int tid = threadIdx.x;
    const int w = tid >> 6, l = tid & 63;
    const int fr = l & 15;
    const int g  = l >> 4;
    const int jw = w * 16;            // wave's 16-col j window in tile

    // ---- (1) stage lI: linear LDS dest, pre-swizzled global src ----
    #pragma unroll
    for (int it = 0; it < 4; ++it) {
        const int chunk = it * 8 + w;            // 1 KB chunks, 32 total
        const int row = chunk * 4 + (l >> 4);
        const int src = ((l & 15) * 16) ^ ((row & 7) << 4);
        async16((char*)lI + chunk * 1024, (const char*)(Fbf + (size_t)(gi + row) * DD) + src);
    }
    if (w < 2) {
        float* dstb = sqi + w * 64;
        async4(dstb, sq + gi + w * 64 + l);
    }

    // ---- (2) A-fragments + sq_j direct from L2 (drained at barrier) ----
    bf16x8 af[4];
    #pragma unroll
    for (int kk = 0; kk < 4; ++kk)
        af[kk] = *(const bf16x8*)(Fbf + (size_t)(gj + jw + fr) * DD + kk * 32 + g * 8);
    const float4 sjv = *(const float4*)(sq + gj + jw + g * 4);

    // ---- (3) barrier: drains lI staging + af/sjv (all L2-fast) ----
    __syncthreads();

    // ---- (4) S loads post-barrier: fly under ds_reads + MFMAs ----
    f32x4 sv[8];
    const float* sb = S + (size_t)(gi + fr) * NN + gj + jw + g * 4;
    #pragma unroll
    for (int ct = 0; ct < 8; ++ct)
        sv[ct] = *(const f32x4*)(sb + (size_t)ct * 16 * NN);
    __builtin_amdgcn_sched_barrier(0);   // pin: S issued before MFMA/ds_read

    f32x4 acc[8];
    #pragma unroll
    for (int ct = 0; ct < 8; ++ct) acc[ct] = (f32x4){0.f, 0.f, 0.f, 0.f};

    // ---- (5) MFMA: D = F_j . F_i^T (S in flight underneath) ----
    #pragma unroll
    for (int ct = 0; ct < 8; ++ct) {
        const int row = ct * 16 + fr;
        const int sw  = (row & 7) << 4;
        #pragma unroll
        for (int kk = 0; kk < 4; ++kk) {
            const bf16x8 bfrag = *(const bf16x8*)((const char*)lI + row * 256 +
                                                  ((kk * 64 + g * 16) ^ sw));
            acc[ct] = __builtin_amdgcn_mfma_f32_16x16x32_bf16(af[kk], bfrag, acc[ct], 0, 0, 0);
        }
    }

    // ---- (6) consume: part += S * (sq_i + sq_j - 2*P) ----
    float part0 = 0.f, part1 = 0.f;
    #pragma unroll
    for (int ct = 0; ct < 8; ++ct) {
        const float sic = sqi[ct * 16 + fr];
        const f32x4 s4 = sv[ct];
        part0 += s4.x * ((sic + sjv.x) - 2.f * acc[ct][0]);
        part1 += s4.y * ((sic + sjv.y) - 2.f * acc[ct][1]);
        part0 += s4.z * ((sic + sjv.z) - 2.f * acc[ct][2]);
        part1 += s4.w * ((sic + sjv.w) - 2.f * acc[ct][3]);
    }
    float part = part0 + part1;

    // ---- (7) deterministic block reduction ----
    #pragma unroll
    for (int off = 32; off > 0; off >>= 1) part += __shfl_down(part, off);
    if (l == 0) red[w] = part;
    __syncthreads();
    if (tid == 0)
        partials[blockIdx.y * gridDim.x + blockIdx.x] =
            ((red[0] + red[1]) + (red[2] + red[3])) +
            ((red[4] + red[5]) + (red[6] + red[7]));
}

// ---------------- fallback path (tiny workspace): R2-style ----------------
__global__ __launch_bounds__(256, 2) void tile_fb_kernel(
        const float* __restrict__ F, const float* __restrict__ S,
        const float* __restrict__ sq, float* __restrict__ partials) {
    __shared__ ushort lI[BM * DD];
    __shared__ ushort lJ[BM * DD];
    __shared__ float  sqi[BM];
    __shared__ float  sqj[BM];
    __shared__ float  red[4];

    const int gi = blockIdx.y * BM, gj = blockIdx.x * BM;
    const int tid = threadIdx.x;
    const int w = tid >> 6, l = tid & 63;

    const int r0 = tid >> 5;
    const int c4 = (tid & 31) * 4;
    #pragma unroll
    for (int it = 0; it < 16; ++it) {
        const int row = it * 8 + r0;
        const float4 va = *(const float4*)(F + (size_t)(gi + row) * DD + c4);
        const float4 vb = *(const float4*)(F + (size_t)(gj + row) * DD + c4);
        int byte = row * 256 + c4 * 2;
        byte ^= (row & 7) << 4;
        *(ushort4*)((char*)lI + byte) =
            make_ushort4(f2bf(va.x), f2bf(va.y), f2bf(va.z), f2bf(va.w));
        *(ushort4*)((char*)lJ + byte) =
            make_ushort4(f2bf(vb.x), f2bf(vb.y), f2bf(vb.z), f2bf(vb.w));
    }
    if (tid < 128) sqi[tid] = sq[gi + tid];
    else           sqj[tid - 128] = sq[gj + tid - 128];
    __syncthreads();

    const int fr = l & 15;
    const int g  = l >> 4;
    const int jw = w * 32;

    float4 sv0[8], sv1[8];
    #pragma unroll
    for (int ct = 0; ct < 8; ++ct) {
        const float* srow = S + (size_t)(gi + ct * 16 + fr) * NN + gj + jw + g * 4;
        sv0[ct] = *(const float4*)(srow);
        sv1[ct] = *(const float4*)(srow + 16);
    }

    bf16x8 afrag[2][4];
    #pragma unroll
    for (int kk = 0; kk < 4; ++kk) {
        int row = jw + fr;
        int byte = row * 256 + kk * 64 + g * 16; byte ^= (row & 7) << 4;
        afrag[0][kk] = *(const bf16x8*)((const char*)lJ + byte);
        row = jw + 16 + fr;
        byte = row * 256 + kk * 64 + g * 16; byte ^= (row & 7) << 4;
        afrag[1][kk] = *(const bf16x8*)((const char*)lJ + byte);
    }

    f32x4 acc[2][8];
    #pragma unroll
    for (int ct = 0; ct < 8; ++ct) {
        acc[0][ct] = (f32x4){0.f, 0.f, 0.f, 0.f};
        acc[1][ct] = (f32x4){0.f, 0.f, 0.f, 0.f};
    }
    #pragma unroll
    for (int ct = 0; ct < 8; ++ct) {
        #pragma unroll
        for (int kk = 0; kk < 4; ++kk) {
            const int row = ct * 16 + fr;
            int byte = row * 256 + kk * 64 + g * 16; byte ^= (row & 7) << 4;
            const bf16x8 bfrag = *(const bf16x8*)((const char*)lI + byte);
            acc[0][ct] = __builtin_amdgcn_mfma_f32_16x16x32_bf16(afrag[0][kk], bfrag, acc[0][ct], 0, 0, 0);
            acc[1][ct] = __builtin_amdgcn_mfma_f32_16x16x32_bf16(afrag[1][kk], bfrag, acc[1][ct], 0, 0, 0);
        }
    }

    const float4 sj0 = *(const float4*)(sqj + jw + g * 4);
    const float4 sj1 = *(const float4*)(sqj + jw + 16 + g * 4);
    float part = 0.f;
    #pragma unroll
    for (int ct = 0; ct < 8; ++ct) {
        const float sic = sqi[ct * 16 + fr];
        const float4 s0 = sv0[ct], s1 = sv1[ct];
        part += s0.x * (sic + sj0.x - 2.f * acc[0][ct][0]);
        part += s0.y * (sic + sj0.y - 2.f * acc[0][ct][1]);
        part += s0.z * (sic + sj0.z - 2.f * acc[0][ct][2]);
        part += s0.w * (sic + sj0.w - 2.f * acc[0][ct][3]);
        part += s1.x * (sic + sj1.x - 2.f * acc[1][ct][0]);
        part += s1.y * (sic + sj1.y - 2.f * acc[1][ct][1]);
        part += s1.z * (sic + sj1.z - 2.f * acc[1][ct][2]);
        part += s1.w * (sic + sj1.w - 2.f * acc[1][ct][3]);
    }

    #pragma unroll
    for (int off = 32; off > 0; off >>= 1) part += __shfl_down(part, off);
    if (l == 0) red[w] = part;
    __syncthreads();
    if (tid == 0)
        partials[blockIdx.y * gridDim.x + blockIdx.x] = (red[0] + red[1]) + (red[2] + red[3]);
}

__global__ void reduce_kernel(const float* __restrict__ partials, float* __restrict__ out) {
    __shared__ float sm[256];
    const int t = threadIdx.x;
    float s = 0.f;
    for (int i = t; i < NTILE * NTILE; i += 256) s += partials[i];
    sm[t] = s;
    __syncthreads();
    for (int off = 128; off > 0; off >>= 1) {
        if (t < off) sm[t] += sm[t + off];
        __syncthreads();
    }
    if (t == 0) out[0] = sm[0];
}

extern "C" void kernel_launch(void* const* d_in, const int* in_sizes, int n_in,
                              void* d_out, int out_size, void* d_ws, size_t ws_size,
                              hipStream_t stream) {
    const float* F = (const float*)d_in[0];
    const float* S = (const float*)d_in[1];
    float* sq       = (float*)d_ws;                       // 32 KB
    float* partials = sq + NN;                            // 16 KB
    ushort* Fbf     = (ushort*)((char*)d_ws + 48 * 1024); // 2 MB
    float* out      = (float*)d_out;

    const size_t need = 48 * 1024 + (size_t)NN * DD * 2 + 256;
    const int fast = (ws_size >= need) ? 1 : 0;

    prep_kernel<<<NN / 4, 256, 0, stream>>>(F, Fbf, sq, fast);
    dim3 grid(NTILE, NTILE);
    if (fast)
        tile_kernel<<<grid, 512, 0, stream>>>(Fbf, S, sq, partials);
    else
        tile_fb_kernel<<<grid, 256, 0, stream>>>(F, S, sq, partials);
    reduce_kernel<<<1, 256, 0, stream>>>(partials, out);
}

// Round 16
// 63.763 us; speedup vs baseline: 1.4757x; 1.1249x over previous
//
#include <hip/hip_runtime.h>

#define NN 8192
#define DD 128
#define BM 128
#define NTILE (NN / BM)   // 64

typedef __attribute__((ext_vector_type(8))) short bf16x8;
typedef __attribute__((ext_vector_type(4))) float f32x4;

__device__ __forceinline__ ushort f2bf(float x) {
    unsigned u = __float_as_uint(x);
    unsigned r = u + 0x7FFFu + ((u >> 16) & 1u);
    return (ushort)(r >> 16);
}

__device__ __forceinline__ void async16(void* lds, const void* g) {
    __builtin_amdgcn_global_load_lds(
        (const __attribute__((address_space(1))) unsigned*)g,
        (__attribute__((address_space(3))) unsigned*)lds, 16, 0, 0);
}
__device__ __forceinline__ void async4(void* lds, const void* g) {
    __builtin_amdgcn_global_load_lds(
        (const __attribute__((address_space(1))) unsigned*)g,
        (__attribute__((address_space(3))) unsigned*)lds, 4, 0, 0);
}

// Kernel 0: sq[i] = ||f_i||^2 (always); Fbf = bf16(F) (if doFbf).
__global__ void prep_kernel(const float* __restrict__ F, ushort* __restrict__ Fbf,
                            float* __restrict__ sq, int doFbf) {
    int gtid = blockIdx.x * blockDim.x + threadIdx.x;
    int row  = gtid >> 6;
    int lane = threadIdx.x & 63;
    const float2 v = *(const float2*)(F + (size_t)row * DD + lane * 2);
    if (doFbf)
        ((ushort2*)(Fbf + (size_t)row * DD))[lane] = make_ushort2(f2bf(v.x), f2bf(v.y));
    float s = v.x * v.x + v.y * v.y;
    #pragma unroll
    for (int off = 32; off > 0; off >>= 1) s += __shfl_down(s, off);
    if (lane == 0) sq[row] = s;
}

// Kernel 1 (fast): R10 champion, verbatim (measured 64.1us).
// Per 128x128 S-tile: partial = sum S_ij*(sq_i+sq_j-2*f_i.f_j).
// 512-thread blocks (8 waves, 16-col j-window each, ~105 VGPR -> 16 waves/CU);
// both panels staged via global_load_lds (coalesced, linear LDS dest +
// pre-swizzled global src); S loads issued AFTER the barrier so they fly
// under the ds_read+MFMA phase. Survived 5 single-variable challenges
// (S-before-barrier, 32 waves/CU, persistent+vmcnt, XCD swizzle, direct-af).
__global__ __launch_bounds__(512, 4) void tile_kernel(
        const ushort* __restrict__ Fbf, const float* __restrict__ S,
        const float* __restrict__ sq, float* __restrict__ partials) {
    __shared__ ushort lI[BM * DD];   // F_i panel (B-operand), swizzled (32 KB)
    __shared__ ushort lJ[BM * DD];   // F_j panel (A-operand), swizzled (32 KB)
    __shared__ float  sqi[BM];
    __shared__ float  sqj[BM];
    __shared__ float  red[8];

    const int gi = blockIdx.y * BM, gj = blockIdx.x * BM;
    const int tid = threadIdx.x;
    const int w = tid >> 6, l = tid & 63;

    // ---- stage panels: linear LDS dest, pre-swizzled global src ----
    #pragma unroll
    for (int it = 0; it < 4; ++it) {
        const int chunk = it * 8 + w;            // 1 KB chunks, 32 per panel
        const int row = chunk * 4 + (l >> 4);    // LDS row this lane lands in
        const int src = ((l & 15) * 16) ^ ((row & 7) << 4);
        async16((char*)lI + chunk * 1024, (const char*)(Fbf + (size_t)(gi + row) * DD) + src);
        async16((char*)lJ + chunk * 1024, (const char*)(Fbf + (size_t)(gj + row) * DD) + src);
    }
    if (w < 4) {
        float* dstb = (w < 2 ? sqi : sqj) + (w & 1) * 64;
        const float* srcb = sq + (w < 2 ? gi : gj) + (w & 1) * 64 + l;
        async4(dstb, srcb);
    }
    __syncthreads();

    const int fr = l & 15;
    const int g  = l >> 4;
    const int jw = w * 16;            // wave's 16-col j window in tile

    // ---- S loads after barrier: fly under ds_reads + MFMAs ----
    f32x4 sv[8];
    const float* sb = S + (size_t)(gi + fr) * NN + gj + jw + g * 4;
    #pragma unroll
    for (int ct = 0; ct < 8; ++ct)
        sv[ct] = *(const f32x4*)(sb + (size_t)ct * 16 * NN);
    __builtin_amdgcn_sched_barrier(0);   // pin: S issued before MFMA/ds_read

    // ---- A fragments from F_j panel ----
    bf16x8 afrag[4];
    #pragma unroll
    for (int kk = 0; kk < 4; ++kk) {
        const int row = jw + fr;
        int byte = row * 256 + kk * 64 + g * 16;
        byte ^= (row & 7) << 4;
        afrag[kk] = *(const bf16x8*)((const char*)lJ + byte);
    }

    f32x4 acc[8];
    #pragma unroll
    for (int ct = 0; ct < 8; ++ct) acc[ct] = (f32x4){0.f, 0.f, 0.f, 0.f};

    // ---- MFMA: D = F_j . F_i^T (S loads in flight underneath) ----
    #pragma unroll
    for (int ct = 0; ct < 8; ++ct) {
        const int row = ct * 16 + fr;
        const int sw  = (row & 7) << 4;
        #pragma unroll
        for (int kk = 0; kk < 4; ++kk) {
            const bf16x8 bfrag = *(const bf16x8*)((const char*)lI + row * 256 +
                                                  ((kk * 64 + g * 16) ^ sw));
            acc[ct] = __builtin_amdgcn_mfma_f32_16x16x32_bf16(afrag[kk], bfrag, acc[ct], 0, 0, 0);
        }
    }

    // ---- consume: part += S * (sq_i + sq_j - 2*P) ----
    const float4 sjv = *(const float4*)(sqj + jw + g * 4);
    float part0 = 0.f, part1 = 0.f;
    #pragma unroll
    for (int ct = 0; ct < 8; ++ct) {
        const float sic = sqi[ct * 16 + fr];
        const f32x4 s4 = sv[ct];
        part0 += s4.x * ((sic + sjv.x) - 2.f * acc[ct][0]);
        part1 += s4.y * ((sic + sjv.y) - 2.f * acc[ct][1]);
        part0 += s4.z * ((sic + sjv.z) - 2.f * acc[ct][2]);
        part1 += s4.w * ((sic + sjv.w) - 2.f * acc[ct][3]);
    }
    float part = part0 + part1;

    // ---- deterministic block reduction ----
    #pragma unroll
    for (int off = 32; off > 0; off >>= 1) part += __shfl_down(part, off);
    if (l == 0) red[w] = part;
    __syncthreads();
    if (tid == 0)
        partials[blockIdx.y * gridDim.x + blockIdx.x] =
            ((red[0] + red[1]) + (red[2] + red[3])) +
            ((red[4] + red[5]) + (red[6] + red[7]));
}

// ---------------- fallback path (tiny workspace): R2-style ----------------
__global__ __launch_bounds__(256, 2) void tile_fb_kernel(
        const float* __restrict__ F, const float* __restrict__ S,
        const float* __restrict__ sq, float* __restrict__ partials) {
    __shared__ ushort lI[BM * DD];
    __shared__ ushort lJ[BM * DD];
    __shared__ float  sqi[BM];
    __shared__ float  sqj[BM];
    __shared__ float  red[4];

    const int gi = blockIdx.y * BM, gj = blockIdx.x * BM;
    const int tid = threadIdx.x;
    const int w = tid >> 6, l = tid & 63;

    const int r0 = tid >> 5;
    const int c4 = (tid & 31) * 4;
    #pragma unroll
    for (int it = 0; it < 16; ++it) {
        const int row = it * 8 + r0;
        const float4 va = *(const float4*)(F + (size_t)(gi + row) * DD + c4);
        const float4 vb = *(const float4*)(F + (size_t)(gj + row) * DD + c4);
        int byte = row * 256 + c4 * 2;
        byte ^= (row & 7) << 4;
        *(ushort4*)((char*)lI + byte) =
            make_ushort4(f2bf(va.x), f2bf(va.y), f2bf(va.z), f2bf(va.w));
        *(ushort4*)((char*)lJ + byte) =
            make_ushort4(f2bf(vb.x), f2bf(vb.y), f2bf(vb.z), f2bf(vb.w));
    }
    if (tid < 128) sqi[tid] = sq[gi + tid];
    else           sqj[tid - 128] = sq[gj + tid - 128];
    __syncthreads();

    const int fr = l & 15;
    const int g  = l >> 4;
    const int jw = w * 32;

    float4 sv0[8], sv1[8];
    #pragma unroll
    for (int ct = 0; ct < 8; ++ct) {
        const float* srow = S + (size_t)(gi + ct * 16 + fr) * NN + gj + jw + g * 4;
        sv0[ct] = *(const float4*)(srow);
        sv1[ct] = *(const float4*)(srow + 16);
    }

    bf16x8 afrag[2][4];
    #pragma unroll
    for (int kk = 0; kk < 4; ++kk) {
        int row = jw + fr;
        int byte = row * 256 + kk * 64 + g * 16; byte ^= (row & 7) << 4;
        afrag[0][kk] = *(const bf16x8*)((const char*)lJ + byte);
        row = jw + 16 + fr;
        byte = row * 256 + kk * 64 + g * 16; byte ^= (row & 7) << 4;
        afrag[1][kk] = *(const bf16x8*)((const char*)lJ + byte);
    }

    f32x4 acc[2][8];
    #pragma unroll
    for (int ct = 0; ct < 8; ++ct) {
        acc[0][ct] = (f32x4){0.f, 0.f, 0.f, 0.f};
        acc[1][ct] = (f32x4){0.f, 0.f, 0.f, 0.f};
    }
    #pragma unroll
    for (int ct = 0; ct < 8; ++ct) {
        #pragma unroll
        for (int kk = 0; kk < 4; ++kk) {
            const int row = ct * 16 + fr;
            int byte = row * 256 + kk * 64 + g * 16; byte ^= (row & 7) << 4;
            const bf16x8 bfrag = *(const bf16x8*)((const char*)lI + byte);
            acc[0][ct] = __builtin_amdgcn_mfma_f32_16x16x32_bf16(afrag[0][kk], bfrag, acc[0][ct], 0, 0, 0);
            acc[1][ct] = __builtin_amdgcn_mfma_f32_16x16x32_bf16(afrag[1][kk], bfrag, acc[1][ct], 0, 0, 0);
        }
    }

    const float4 sj0 = *(const float4*)(sqj + jw + g * 4);
    const float4 sj1 = *(const float4*)(sqj + jw + 16 + g * 4);
    float part = 0.f;
    #pragma unroll
    for (int ct = 0; ct < 8; ++ct) {
        const float sic = sqi[ct * 16 + fr];
        const float4 s0 = sv0[ct], s1 = sv1[ct];
        part += s0.x * (sic + sj0.x - 2.f * acc[0][ct][0]);
        part += s0.y * (sic + sj0.y - 2.f * acc[0][ct][1]);
        part += s0.z * (sic + sj0.z - 2.f * acc[0][ct][2]);
        part += s0.w * (sic + sj0.w - 2.f * acc[0][ct][3]);
        part += s1.x * (sic + sj1.x - 2.f * acc[1][ct][0]);
        part += s1.y * (sic + sj1.y - 2.f * acc[1][ct][1]);
        part += s1.z * (sic + sj1.z - 2.f * acc[1][ct][2]);
        part += s1.w * (sic + sj1.w - 2.f * acc[1][ct][3]);
    }

    #pragma unroll
    for (int off = 32; off > 0; off >>= 1) part += __shfl_down(part, off);
    if (l == 0) red[w] = part;
    __syncthreads();
    if (tid == 0)
        partials[blockIdx.y * gridDim.x + blockIdx.x] = (red[0] + red[1]) + (red[2] + red[3]);
}

__global__ void reduce_kernel(const float* __restrict__ partials, float* __restrict__ out) {
    __shared__ float sm[256];
    const int t = threadIdx.x;
    float s = 0.f;
    for (int i = t; i < NTILE * NTILE; i += 256) s += partials[i];
    sm[t] = s;
    __syncthreads();
    for (int off = 128; off > 0; off >>= 1) {
        if (t < off) sm[t] += sm[t + off];
        __syncthreads();
    }
    if (t == 0) out[0] = sm[0];
}

extern "C" void kernel_launch(void* const* d_in, const int* in_sizes, int n_in,
                              void* d_out, int out_size, void* d_ws, size_t ws_size,
                              hipStream_t stream) {
    const float* F = (const float*)d_in[0];
    const float* S = (const float*)d_in[1];
    float* sq       = (float*)d_ws;                       // 32 KB
    float* partials = sq + NN;                            // 16 KB
    ushort* Fbf     = (ushort*)((char*)d_ws + 48 * 1024); // 2 MB
    float* out      = (float*)d_out;

    const size_t need = 48 * 1024 + (size_t)NN * DD * 2 + 256;
    const int fast = (ws_size >= need) ? 1 : 0;

    prep_kernel<<<NN / 4, 256, 0, stream>>>(F, Fbf, sq, fast);
    dim3 grid(NTILE, NTILE);
    if (fast)
        tile_kernel<<<grid, 512, 0, stream>>>(Fbf, S, sq, partials);
    else
        tile_fb_kernel<<<grid, 256, 0, stream>>>(F, S, sq, partials);
    reduce_kernel<<<1, 256, 0, stream>>>(partials, out);
}